// Round 3
// baseline (7824.244 us; speedup 1.0000x reference)
//
#include <hip/hip_runtime.h>

#define TSEQ 2048
#define NB   20
#define NIN  256
#define NH   512
#define NOUT 128

typedef unsigned int   u32;
typedef unsigned short u16;
typedef _Float16 f16x2 __attribute__((ext_vector_type(2)));

// dynamic LDS layout
#define SM_W     0                 // 131072 B: WLw uint4[16][512] (recurrence) / WL uint2[32][512] (pre1)
#define SM_HX    131072            // 1024 B: h exchange, f16[512]
#define SM_INP   (131072 + 1024)   // 2048 B: u32 [2][256] input staging (pre roles)
#define SMEM_BYTES (131072 + 1024 + 2048)

__device__ __forceinline__ u32 packh2(float a, float b) {
  f16x2 p; p.x = (_Float16)a; p.y = (_Float16)b;
  return __builtin_bit_cast(u32, p);
}

__device__ __forceinline__ float dot2(u32 w, u32 h, float acc) {
  return __builtin_amdgcn_fdot2(__builtin_bit_cast(f16x2, w),
                                __builtin_bit_cast(f16x2, h), acc, false);
}

__device__ __forceinline__ int acq(const int* p) {
  return __hip_atomic_load(p, __ATOMIC_ACQUIRE, __HIP_MEMORY_SCOPE_AGENT);
}
__device__ __forceinline__ void rel(int* p, int v) {
  __hip_atomic_store(p, v, __ATOMIC_RELEASE, __HIP_MEMORY_SCOPE_AGENT);
}

// cross-lane add via DPP (VALU pipe, no LDS). CTRL: 0x140 row_mirror (xor15),
// 0x141 row_half_mirror (xor7), 0x4E quad[2,3,0,1] (xor2), 0xB1 quad[1,0,3,2] (xor1)
template<int CTRL>
__device__ __forceinline__ float dpp_add(float x) {
  int v = __builtin_amdgcn_update_dpp(0, __builtin_bit_cast(int, x), CTRL, 0xF, 0xF, true);
  return x + __builtin_bit_cast(float, v);
}

__device__ __forceinline__ float fast_tanh(float x) {
  float xc = fminf(fmaxf(x, -15.f), 15.f);
  float e = __builtin_amdgcn_exp2f(xc * 2.8853900817779268f);  // exp(2x)
  return (e - 1.f) * __builtin_amdgcn_rcpf(e + 1.f);
}

// Persistent fused pipeline. grid = 140 blocks x 512 threads, 1 block/CU.
//  bid   0..39 : pre0 (b=bid>>1, half=bid&1)       pre0 = x@Wih0^T + bih0 (f16)
//  bid  40..59 : L0 recurrence (b=bid-40), scatter/DPP-reduce; out0 = h packed f16
//  bid 60..119 : pre1 (b=(bid-60)/3, sub=(bid-60)%3) 3-way t-chunked gather
//  bid120..139 : L1 recurrence (b=bid-120); h1f = last h (f32)
__global__ __launch_bounds__(512) __attribute__((amdgpu_waves_per_eu(2, 2)))
void rnn_persist(
    const float* __restrict__ x,    const float* __restrict__ h0,
    const float* __restrict__ Wih0, const float* __restrict__ Whh0,
    const float* __restrict__ bih0, const float* __restrict__ bhh0,
    const float* __restrict__ Wih1, const float* __restrict__ Whh1,
    const float* __restrict__ bih1, const float* __restrict__ bhh1,
    u16* __restrict__ pre0, u32* __restrict__ out0,
    u16* __restrict__ pre1, float* __restrict__ h1f,
    int* __restrict__ flags)
{
  extern __shared__ char smem[];
  const int tid = threadIdx.x;
  const int bid = blockIdx.x;

  if (bid < 40) {
    // ---------------- pre0: x @ Wih0^T + bih0 (unchanged, verified) ----------------
    u32* inp = (u32*)(smem + SM_INP);
    const int b = bid >> 1, half = bid & 1, t0 = half * 1024;
    const int n = tid;
    u32 wr[128];
    const float4* W4 = (const float4*)(Wih0 + (size_t)n * NIN);
#pragma unroll
    for (int j = 0; j < 64; j++) {
      float4 w = W4[j];
      wr[2*j] = packh2(w.x, w.y); wr[2*j+1] = packh2(w.z, w.w);
    }
    const float bias = bih0[n];
    const float* xb = x + ((size_t)b * TSEQ + t0) * NIN;
    u16* op = pre0 + ((size_t)b * TSEQ + t0) * NH;

    float2 r = make_float2(0.f, 0.f);
    if (tid < 128) r = ((const float2*)xb)[tid];
    int cur = 0;
    for (int t = 0; t < 1024; t++) {
      if (tid < 128) inp[cur * 256 + tid] = packh2(r.x, r.y);
      __syncthreads();
      if (t + 1 < 1024 && tid < 128)
        r = ((const float2*)(xb + (size_t)(t + 1) * NIN))[tid];
      float a0 = bias, a1 = 0.f;
      const uint4* xp = (const uint4*)(inp + cur * 256);
#pragma unroll
      for (int j = 0; j < 32; j++) {
        uint4 hv = xp[j];
        a0 = dot2(wr[4*j+0], hv.x, a0); a1 = dot2(wr[4*j+1], hv.y, a1);
        a0 = dot2(wr[4*j+2], hv.z, a0); a1 = dot2(wr[4*j+3], hv.w, a1);
      }
      op[(size_t)t * NH + n] = __builtin_bit_cast(u16, (_Float16)(a0 + a1));
      cur ^= 1;
      if (((t + 1) & 7) == 0) {
        __syncthreads();
        if (tid == 0) rel(flags + bid * 32, t + 1);
      }
    }
    return;
  }

  if (bid >= 60 && bid < 120) {
    // ---------------- pre1: out0 @ Wih1^T + bih1, 3-way t-chunk split ----------------
    uint2* WL  = (uint2*)(smem + SM_W);
    u32*   inp = (u32*)(smem + SM_INP);
    const int b = (bid - 60) / 3, sub = (bid - 60) % 3;
    const int n = tid;
    u32 wr[192];
    const float4* W4 = (const float4*)(Wih1 + (size_t)n * NH);
#pragma unroll
    for (int j = 0; j < 96; j++) {
      float4 w = W4[j];
      wr[2*j] = packh2(w.x, w.y); wr[2*j+1] = packh2(w.z, w.w);
    }
#pragma unroll
    for (int j2 = 0; j2 < 32; j2++) {
      float4 w = W4[96 + j2];
      WL[j2 * NH + n] = make_uint2(packh2(w.x, w.y), packh2(w.z, w.w));
    }
    const float bias = bih1[n];
    __syncthreads();

    const u32* ip = out0 + (size_t)b * TSEQ * 256;
    u16* op = pre1 + (size_t)b * TSEQ * NH;
    const int* flagOut0 = flags + (40 + b) * 32;
    int* flagMy = flags + (60 + b * 3 + sub) * 32;
    int seen = 0, cur = 0;
#pragma unroll 1
    for (int c = sub; c < TSEQ / 8; c += 3) {
      const int tbase = c * 8;
      while (seen < tbase + 8) seen = acq(flagOut0);
      u32 rin = (tid < 256) ? ip[(size_t)tbase * 256 + tid] : 0;
#pragma unroll 1
      for (int qq = 0; qq < 8; qq++) {
        const int t = tbase + qq;
        if (tid < 256) inp[cur * 256 + tid] = rin;
        __syncthreads();
        if (qq + 1 < 8 && tid < 256) rin = ip[(size_t)(t + 1) * 256 + tid];
        float a0 = bias, a1 = 0.f;
        const uint4* hp4 = (const uint4*)(inp + cur * 256);
#pragma unroll
        for (int j = 0; j < 48; j++) {
          uint4 hv = hp4[j];
          a0 = dot2(wr[4*j+0], hv.x, a0); a1 = dot2(wr[4*j+1], hv.y, a1);
          a0 = dot2(wr[4*j+2], hv.z, a0); a1 = dot2(wr[4*j+3], hv.w, a1);
        }
#pragma unroll
        for (int jj = 0; jj < 16; jj++) {
          uint4 hv = hp4[48 + jj];
          uint2 w0 = WL[(2*jj)   * NH + n];
          uint2 w1 = WL[(2*jj+1) * NH + n];
          a0 = dot2(w0.x, hv.x, a0); a1 = dot2(w0.y, hv.y, a1);
          a0 = dot2(w1.x, hv.z, a0); a1 = dot2(w1.y, hv.w, a1);
        }
        op[(size_t)t * NH + n] = __builtin_bit_cast(u16, (_Float16)(a0 + a1));
        cur ^= 1;
      }
      __syncthreads();
      if (tid == 0) rel(flagMy, tbase + 8);
    }
    return;
  }

  // ---------------- L0 / L1 recurrence: scatter + 16-lane DPP butterfly ----------------
  const bool isL0 = (bid < 60);
  const int b = isL0 ? (bid - 40) : (bid - 120);
  const float* Wg = isL0 ? Whh0 : Whh1;
  const float* bp = isL0 ? bhh0 : bhh1;

  uint4* WLw = (uint4*)(smem + SM_W);   // [16][512]
  u16*   hx  = (u16*)(smem + SM_HX);    // f16[512]

  const int lam = tid & 15;             // k-group: k in [32*lam, 32*lam+32)
  const int ns  = tid >> 4;             // n-slice: rows 16*ns .. 16*ns+15

  // Weights: rows 16*ns+j, cols 32*lam..+32. j<12 in regs, j>=12 in LDS [i][tid] layout.
  u32 wj[12][16];
#pragma unroll
  for (int j = 0; j < 16; j++) {
    const float4* Wr = (const float4*)(Wg + (size_t)(16 * ns + j) * NH + 32 * lam);
    u32 tmp[16];
#pragma unroll
    for (int i4 = 0; i4 < 8; i4++) {
      float4 w = Wr[i4];
      tmp[2*i4] = packh2(w.x, w.y); tmp[2*i4+1] = packh2(w.z, w.w);
    }
    if (j < 12) {
#pragma unroll
      for (int i = 0; i < 16; i++) wj[j][i] = tmp[i];
    } else {
#pragma unroll
      for (int q = 0; q < 4; q++)
        WLw[((j - 12) * 4 + q) * 512 + tid] =
            make_uint4(tmp[4*q], tmp[4*q+1], tmp[4*q+2], tmp[4*q+3]);
    }
  }
  const float bias = bp[tid];           // final owner n == tid

  // init h exchange buffer with h0
  hx[tid] = __builtin_bit_cast(u16, (_Float16)h0[((isL0 ? 0 : 1) * NB + b) * NH + tid]);
  __syncthreads();

  const u16* pin = (isL0 ? pre0 : pre1) + (size_t)b * TSEQ * NH;
  u32* o0p = out0 + (size_t)b * TSEQ * 256;
  int* flagOut0 = flags + (40 + b) * 32;
  const int* f0 = flags + (b * 2 + 0) * 32;       // pre0 halves (L0)
  const int* f1 = flags + (b * 2 + 1) * 32;
  const int* fp0 = flags + (60 + b * 3 + 0) * 32; // pre1 subs (L1)
  const int* fp1 = flags + (60 + b * 3 + 1) * 32;
  const int* fp2 = flags + (60 + b * 3 + 2) * 32;
  int s0 = 0, s1 = 0, sA = 0, sB = 0, sC = 0;

  if (isL0) { while (s0 < 1) s0 = acq(f0); }
  else      { while (sA < 1) sA = acq(fp0); }
  u16 pcur = pin[tid];

  const uint4* HX4 = (const uint4*)hx;
  float hlast = 0.f;
#pragma unroll 1
  for (int t = 0; t < TSEQ; t++) {
    // prefetch next pre-activation (issued early; hides under compute)
    u16 pnxt = 0;
    if (t + 1 < TSEQ) {
      if (isL0) {
        const int hf = (t + 1) >> 10, lc = (t + 1) & 1023;
        if (hf == 0) { while (s0 < lc + 1) s0 = acq(f0); }
        else         { while (s1 < lc + 1) s1 = acq(f1); }
      } else {
        const int tn = t + 1;
        const int cm = (tn >> 3) % 3;
        if (cm == 0)      { while (sA < tn + 1) sA = acq(fp0); }
        else if (cm == 1) { while (sB < tn + 1) sB = acq(fp1); }
        else              { while (sC < tn + 1) sC = acq(fp2); }
      }
      pnxt = pin[(size_t)(t + 1) * NH + tid];
    }

    float p[16];
#pragma unroll
    for (int i = 0; i < 16; i++) p[i] = 0.f;
#pragma unroll
    for (int h2 = 0; h2 < 2; h2++) {
      uint4 ha = HX4[lam * 4 + h2 * 2 + 0];
      uint4 hb = HX4[lam * 4 + h2 * 2 + 1];
      u32 hh[8] = {ha.x, ha.y, ha.z, ha.w, hb.x, hb.y, hb.z, hb.w};
#pragma unroll
      for (int j = 0; j < 12; j++) {
#pragma unroll
        for (int i = 0; i < 8; i++)
          p[j] = dot2(wj[j][h2 * 8 + i], hh[i], p[j]);
      }
#pragma unroll
      for (int jj = 0; jj < 4; jj++) {
        uint4 wa = WLw[(jj * 4 + h2 * 2 + 0) * 512 + tid];
        uint4 wb = WLw[(jj * 4 + h2 * 2 + 1) * 512 + tid];
        p[12+jj] = dot2(wa.x, hh[0], p[12+jj]);
        p[12+jj] = dot2(wa.y, hh[1], p[12+jj]);
        p[12+jj] = dot2(wa.z, hh[2], p[12+jj]);
        p[12+jj] = dot2(wa.w, hh[3], p[12+jj]);
        p[12+jj] = dot2(wb.x, hh[4], p[12+jj]);
        p[12+jj] = dot2(wb.y, hh[5], p[12+jj]);
        p[12+jj] = dot2(wb.z, hh[6], p[12+jj]);
        p[12+jj] = dot2(wb.w, hh[7], p[12+jj]);
      }
    }

    // butterfly reduce over the 16-lane row; lane lam ends with sum for n = tid
#pragma unroll
    for (int i = 0; i < 16; i++) p[i] = dpp_add<0x140>(p[i]);   // xor15, keep by bit3
    float q[8]; const bool k3 = (tid & 8);
#pragma unroll
    for (int i = 0; i < 8; i++) q[i] = k3 ? p[i + 8] : p[i];
#pragma unroll
    for (int i = 0; i < 8; i++) q[i] = dpp_add<0x141>(q[i]);    // xor7, bit2
    float rr[4]; const bool k2 = (tid & 4);
#pragma unroll
    for (int i = 0; i < 4; i++) rr[i] = k2 ? q[i + 4] : q[i];
#pragma unroll
    for (int i = 0; i < 4; i++) rr[i] = dpp_add<0x4E>(rr[i]);   // xor2, bit1
    float uu[2]; const bool k1 = (tid & 2);
    uu[0] = k1 ? rr[2] : rr[0]; uu[1] = k1 ? rr[3] : rr[1];
    uu[0] = dpp_add<0xB1>(uu[0]); uu[1] = dpp_add<0xB1>(uu[1]); // xor1, bit0
    const float red = (tid & 1) ? uu[1] : uu[0];

    const float h = fast_tanh(red + bias + (float)__builtin_bit_cast(_Float16, pcur));
    hlast = h;
    __syncthreads();   // A: all hx reads done; prev-iter out0 stores drained (vmcnt0)
    if (isL0 && (t & 7) == 0 && t && tid == 0) rel(flagOut0, t);
    hx[tid] = __builtin_bit_cast(u16, (_Float16)h);
    __syncthreads();   // B: hx stable
    if (isL0 && tid < 256) o0p[(size_t)t * 256 + tid] = ((const u32*)hx)[tid];
    pcur = pnxt;
  }
  if (isL0) {
    __syncthreads();
    if (tid == 0) rel(flagOut0, TSEQ);
  } else {
    h1f[(size_t)b * NH + tid] = hlast;
  }
}

__global__ void fc_kernel(const float* __restrict__ h1f, const float* __restrict__ Wfc,
                          const float* __restrict__ bfc, float* __restrict__ out) {
  const int b = blockIdx.x, o = threadIdx.x;  // 20 blocks x 128 threads
  __shared__ float hs[NH];
  for (int i = o; i < NH; i += NOUT) hs[i] = h1f[(size_t)b * NH + i];
  __syncthreads();
  const float4* w4 = (const float4*)(Wfc + (size_t)o * NH);
  const float4* h4 = (const float4*)hs;
  float acc = bfc[o];
#pragma unroll 8
  for (int j = 0; j < NH / 4; j++) {
    float4 w = w4[j], h = h4[j];
    acc += w.x * h.x + w.y * h.y + w.z * h.z + w.w * h.w;
  }
  out[(size_t)b * NOUT + o] = acc;
}

extern "C" void kernel_launch(void* const* d_in, const int* in_sizes, int n_in,
                              void* d_out, int out_size, void* d_ws, size_t ws_size,
                              hipStream_t stream) {
  const float* x    = (const float*)d_in[0];
  const float* h0   = (const float*)d_in[1];
  const float* Wih0 = (const float*)d_in[2];
  const float* Whh0 = (const float*)d_in[3];
  const float* bih0 = (const float*)d_in[4];
  const float* bhh0 = (const float*)d_in[5];
  const float* Wih1 = (const float*)d_in[6];
  const float* Whh1 = (const float*)d_in[7];
  const float* bih1 = (const float*)d_in[8];
  const float* bhh1 = (const float*)d_in[9];
  const float* Wfc  = (const float*)d_in[10];
  const float* bfc  = (const float*)d_in[11];
  float* out = (float*)d_out;

  char* ws = (char*)d_ws;
  size_t off = 0;
  u16* pre0 = (u16*)(ws + off); off += (size_t)NB * TSEQ * NH * 2;
  u32* out0 = (u32*)(ws + off); off += (size_t)NB * TSEQ * (NH / 2) * 4;
  u16* pre1 = (u16*)(ws + off); off += (size_t)NB * TSEQ * NH * 2;
  float* h1f = (float*)(ws + off); off += (size_t)NB * NH * 4;
  int* flags = (int*)(ws + off);
  const size_t flagbytes = 160 * 32 * sizeof(int);

  hipMemsetAsync(flags, 0, flagbytes, stream);
  hipFuncSetAttribute((const void*)rnn_persist,
                      hipFuncAttributeMaxDynamicSharedMemorySize, SMEM_BYTES);
  rnn_persist<<<140, 512, SMEM_BYTES, stream>>>(
      x, h0, Wih0, Whh0, bih0, bhh0, Wih1, Whh1, bih1, bhh1,
      pre0, out0, pre1, h1f, flags);
  fc_kernel<<<NB, NOUT, 0, stream>>>(h1f, Wfc, bfc, out);
}